// Round 1
// baseline (985.985 us; speedup 1.0000x reference)
//
#include <hip/hip_runtime.h>
#include <hip/hip_bf16.h>

typedef unsigned int u32;
typedef unsigned short u16;

#define N_NODES 2048

__device__ __forceinline__ float bflo(u32 u){ return __uint_as_float(u << 16); }
__device__ __forceinline__ float bfhi(u32 u){ return __uint_as_float(u & 0xFFFF0000u); }
__device__ __forceinline__ u32 packbf(float a, float b){
  u32 ua = __float_as_uint(a), ub = __float_as_uint(b);
  u32 ra = (ua + 0x7FFFu + ((ua >> 16) & 1u)) >> 16;
  u32 rb = (ub + 0x7FFFu + ((ub >> 16) & 1u)) >> 16;
  return ra | (rb << 16);
}

// ---------------------------------------------------------------------------
// K1: KNN (K=16, self-excluded) + GCN layer 1 (3->64) fused.
// One block = 256 nodes of one sample; full sample coords in LDS.
// ---------------------------------------------------------------------------
__global__ __launch_bounds__(256) void k1_knn_l1(
    const float* __restrict__ coords, const float* __restrict__ W1,
    const float* __restrict__ b1, int* __restrict__ nbr, u32* __restrict__ x1)
{
  __shared__ float4 c4[N_NODES];   // 32 KB: x,y,z,0
  __shared__ float  w1s[192];
  __shared__ float  b1s[64];
  const int tid = threadIdx.x;
  const int s   = blockIdx.x >> 3;
  const int n0  = (blockIdx.x & 7) << 8;
  const float* cs = coords + (size_t)s * (N_NODES * 3);
  for (int k = tid; k < N_NODES; k += 256)
    c4[k] = make_float4(cs[3*k], cs[3*k+1], cs[3*k+2], 0.0f);
  if (tid < 192) w1s[tid] = W1[tid];
  if (tid < 64)  b1s[tid] = b1[tid];
  __syncthreads();

  const int i = n0 + tid;
  const float4 ci = c4[i];

  float dst[16]; int idx[16];
#pragma unroll
  for (int q = 0; q < 16; ++q) { dst[q] = __builtin_inff(); idx[q] = 0; }

  for (int j0 = 0; j0 < N_NODES; j0 += 4) {
    float d[4];
#pragma unroll
    for (int q = 0; q < 4; ++q) {
      float4 cj = c4[j0 + q];
      float dx = ci.x - cj.x, dy = ci.y - cj.y, dz = ci.z - cj.z;
      float dd = fmaf(dz, dz, fmaf(dy, dy, dx * dx));
      d[q] = ((j0 + q) == i) ? __builtin_inff() : dd;
    }
    float mn = fminf(fminf(d[0], d[1]), fminf(d[2], d[3]));
    if (mn < dst[15]) {
#pragma unroll
      for (int q = 0; q < 4; ++q) {
        if (d[q] < dst[15]) {
          dst[15] = d[q]; idx[15] = j0 + q;
#pragma unroll
          for (int t = 14; t >= 0; --t) {   // bubble up (keep ascending)
            float a = dst[t], b = dst[t+1];
            bool c = b < a;
            dst[t]   = c ? b : a;  dst[t+1] = c ? a : b;
            int ia = idx[t], ib = idx[t+1];
            idx[t]   = c ? ib : ia; idx[t+1] = c ? ia : ib;
          }
        }
      }
    }
  }

  int4* np_ = (int4*)(nbr + (((size_t)s << 11) + i) * 16);
  np_[0] = make_int4(idx[0],  idx[1],  idx[2],  idx[3]);
  np_[1] = make_int4(idx[4],  idx[5],  idx[6],  idx[7]);
  np_[2] = make_int4(idx[8],  idx[9],  idx[10], idx[11]);
  np_[3] = make_int4(idx[12], idx[13], idx[14], idx[15]);

  // layer 1: mean over {self + 16 nbrs} of coords, then 3x64 matmul + ReLU
  float mx = ci.x, my = ci.y, mz = ci.z;
#pragma unroll
  for (int q = 0; q < 16; ++q) { float4 cn = c4[idx[q]]; mx += cn.x; my += cn.y; mz += cn.z; }
  const float inv = 1.0f / 17.0f;
  mx *= inv; my *= inv; mz *= inv;

  u32 pk[32];
#pragma unroll
  for (int o = 0; o < 64; o += 2) {
    float v0 = fmaf(mz, w1s[128+o],   fmaf(my, w1s[64+o],   fmaf(mx, w1s[o],   b1s[o])));
    float v1 = fmaf(mz, w1s[128+o+1], fmaf(my, w1s[64+o+1], fmaf(mx, w1s[o+1], b1s[o+1])));
    pk[o >> 1] = packbf(fmaxf(v0, 0.0f), fmaxf(v1, 0.0f));
  }
  uint4* xo = (uint4*)(x1 + (((size_t)s << 11) + i) * 32);
#pragma unroll
  for (int q = 0; q < 8; ++q)
    xo[q] = make_uint4(pk[4*q], pk[4*q+1], pk[4*q+2], pk[4*q+3]);
}

// ---------------------------------------------------------------------------
// K2: gather-mean of x1 over {nbr, self} + GCN layer 2 (64->128) + ReLU.
// ---------------------------------------------------------------------------
__global__ __launch_bounds__(256) void k2_gcn2(
    const u32* __restrict__ x1, const int* __restrict__ nbr,
    const float* __restrict__ W2, const float* __restrict__ b2,
    u32* __restrict__ x2)
{
  __shared__ float w2s[64 * 128];  // 32 KB
  __shared__ float b2s[128];
  const int tid = threadIdx.x;
  for (int k = tid; k < 64 * 128; k += 256) w2s[k] = W2[k];
  if (tid < 128) b2s[tid] = b2[tid];
  __syncthreads();

  const size_t node = ((size_t)blockIdx.x << 8) + tid;
  const u32* x1base = x1 + ((node >> 11) << 11) * 32;  // sample base
  const int  self   = (int)(node & 2047);
  const int* nb     = nbr + node * 16;

  float m1[64];
  {
    const uint4* r = (const uint4*)(x1base + (size_t)self * 32);
#pragma unroll
    for (int q = 0; q < 8; ++q) {
      uint4 v = r[q];
      m1[8*q+0] = bflo(v.x); m1[8*q+1] = bfhi(v.x);
      m1[8*q+2] = bflo(v.y); m1[8*q+3] = bfhi(v.y);
      m1[8*q+4] = bflo(v.z); m1[8*q+5] = bfhi(v.z);
      m1[8*q+6] = bflo(v.w); m1[8*q+7] = bfhi(v.w);
    }
  }
#pragma unroll
  for (int t = 0; t < 16; ++t) {
    const uint4* r = (const uint4*)(x1base + (size_t)nb[t] * 32);
#pragma unroll
    for (int q = 0; q < 8; ++q) {
      uint4 v = r[q];
      m1[8*q+0] += bflo(v.x); m1[8*q+1] += bfhi(v.x);
      m1[8*q+2] += bflo(v.y); m1[8*q+3] += bfhi(v.y);
      m1[8*q+4] += bflo(v.z); m1[8*q+5] += bfhi(v.z);
      m1[8*q+6] += bflo(v.w); m1[8*q+7] += bfhi(v.w);
    }
  }
  const float inv = 1.0f / 17.0f;
#pragma unroll
  for (int k = 0; k < 64; ++k) m1[k] *= inv;

  u32* xo = x2 + node * 64;
#pragma unroll 1
  for (int oc = 0; oc < 8; ++oc) {          // 8 chunks of 16 outputs
    float acc[16];
#pragma unroll
    for (int q = 0; q < 16; ++q) acc[q] = b2s[oc * 16 + q];
#pragma unroll
    for (int i = 0; i < 64; ++i) {
      const float4* w = (const float4*)&w2s[i * 128 + oc * 16];
      float xi = m1[i];
      float4 w0 = w[0], w1_ = w[1], w2_ = w[2], w3_ = w[3];
      acc[0]  = fmaf(xi, w0.x,  acc[0]);  acc[1]  = fmaf(xi, w0.y,  acc[1]);
      acc[2]  = fmaf(xi, w0.z,  acc[2]);  acc[3]  = fmaf(xi, w0.w,  acc[3]);
      acc[4]  = fmaf(xi, w1_.x, acc[4]);  acc[5]  = fmaf(xi, w1_.y, acc[5]);
      acc[6]  = fmaf(xi, w1_.z, acc[6]);  acc[7]  = fmaf(xi, w1_.w, acc[7]);
      acc[8]  = fmaf(xi, w2_.x, acc[8]);  acc[9]  = fmaf(xi, w2_.y, acc[9]);
      acc[10] = fmaf(xi, w2_.z, acc[10]); acc[11] = fmaf(xi, w2_.w, acc[11]);
      acc[12] = fmaf(xi, w3_.x, acc[12]); acc[13] = fmaf(xi, w3_.y, acc[13]);
      acc[14] = fmaf(xi, w3_.z, acc[14]); acc[15] = fmaf(xi, w3_.w, acc[15]);
    }
    u32 p[8];
#pragma unroll
    for (int q = 0; q < 8; ++q)
      p[q] = packbf(fmaxf(acc[2*q], 0.0f), fmaxf(acc[2*q+1], 0.0f));
    uint4* o4 = (uint4*)(xo + oc * 8);
    o4[0] = make_uint4(p[0], p[1], p[2], p[3]);
    o4[1] = make_uint4(p[4], p[5], p[6], p[7]);
  }
}

// ---------------------------------------------------------------------------
// K3: final linear 128->128 (no aggregation), f32 output.
// ---------------------------------------------------------------------------
__global__ __launch_bounds__(256) void k3_final(
    const u32* __restrict__ x2, const float* __restrict__ Wf,
    const float* __restrict__ bfv, float* __restrict__ out)
{
  __shared__ float wfs[128 * 128];  // 64 KB
  __shared__ float bfs[128];
  const int tid = threadIdx.x;
  {
    const float4* wsrc = (const float4*)Wf;
    float4* wdst = (float4*)wfs;
    for (int k = tid; k < 4096; k += 256) wdst[k] = wsrc[k];
  }
  if (tid < 128) bfs[tid] = bfv[tid];
  __syncthreads();

  const size_t node = ((size_t)blockIdx.x << 8) + tid;
  const uint4* xr = (const uint4*)(x2 + node * 64);
  u32 row[64];
#pragma unroll
  for (int q = 0; q < 16; ++q) {
    uint4 v = xr[q];
    row[4*q] = v.x; row[4*q+1] = v.y; row[4*q+2] = v.z; row[4*q+3] = v.w;
  }

  float* orow = out + node * 128;
#pragma unroll 1
  for (int p = 0; p < 4; ++p) {             // 4 passes of 32 outputs
    float acc[32];
#pragma unroll
    for (int q = 0; q < 32; ++q) acc[q] = bfs[p * 32 + q];
#pragma unroll
    for (int u = 0; u < 64; ++u) {          // 2 input channels per u
      u32 uw = row[u];
      float x0 = bflo(uw), x1v = bfhi(uw);
      {
        const float4* w = (const float4*)&wfs[(2*u) * 128 + p * 32];
#pragma unroll
        for (int q = 0; q < 8; ++q) {
          float4 wv = w[q];
          acc[4*q+0] = fmaf(x0, wv.x, acc[4*q+0]);
          acc[4*q+1] = fmaf(x0, wv.y, acc[4*q+1]);
          acc[4*q+2] = fmaf(x0, wv.z, acc[4*q+2]);
          acc[4*q+3] = fmaf(x0, wv.w, acc[4*q+3]);
        }
      }
      {
        const float4* w = (const float4*)&wfs[(2*u+1) * 128 + p * 32];
#pragma unroll
        for (int q = 0; q < 8; ++q) {
          float4 wv = w[q];
          acc[4*q+0] = fmaf(x1v, wv.x, acc[4*q+0]);
          acc[4*q+1] = fmaf(x1v, wv.y, acc[4*q+1]);
          acc[4*q+2] = fmaf(x1v, wv.z, acc[4*q+2]);
          acc[4*q+3] = fmaf(x1v, wv.w, acc[4*q+3]);
        }
      }
    }
    float4* o4 = (float4*)(orow + p * 32);
#pragma unroll
    for (int q = 0; q < 8; ++q)
      o4[q] = make_float4(acc[4*q], acc[4*q+1], acc[4*q+2], acc[4*q+3]);
  }
}

extern "C" void kernel_launch(void* const* d_in, const int* in_sizes, int n_in,
                              void* d_out, int out_size, void* d_ws, size_t ws_size,
                              hipStream_t stream) {
  const float* coords = (const float*)d_in[0];
  const float* W1 = (const float*)d_in[1];
  const float* b1 = (const float*)d_in[2];
  const float* W2 = (const float*)d_in[3];
  const float* b2 = (const float*)d_in[4];
  const float* Wf = (const float*)d_in[5];
  const float* bf = (const float*)d_in[6];
  float* out = (float*)d_out;

  char* ws = (char*)d_ws;
  int* nbr = (int*)ws;                                  //  4 MB: [32,2048,16] i32
  u32* x1  = (u32*)(ws + (size_t)4  * 1024 * 1024);     //  8 MB: [32,2048,64] bf16
  u32* x2  = (u32*)(ws + (size_t)12 * 1024 * 1024);     // 16 MB: [32,2048,128] bf16

  k1_knn_l1<<<256, 256, 0, stream>>>(coords, W1, b1, nbr, x1);
  k2_gcn2  <<<256, 256, 0, stream>>>(x1, nbr, W2, b2, x2);
  k3_final <<<256, 256, 0, stream>>>(x2, Wf, bf, out);
}

// Round 2
// 664.875 us; speedup vs baseline: 1.4830x; 1.4830x over previous
//
#include <hip/hip_runtime.h>
#include <hip/hip_bf16.h>

typedef unsigned int u32;

#define N_NODES 2048
#define INF __builtin_inff()

__device__ __forceinline__ float bflo(u32 u){ return __uint_as_float(u << 16); }
__device__ __forceinline__ float bfhi(u32 u){ return __uint_as_float(u & 0xFFFF0000u); }
__device__ __forceinline__ u32 packbf(float a, float b){
  u32 ua = __float_as_uint(a), ub = __float_as_uint(b);
  u32 ra = (ua + 0x7FFFu + ((ua >> 16) & 1u)) >> 16;
  u32 rb = (ub + 0x7FFFu + ((ub >> 16) & 1u)) >> 16;
  return ra | (rb << 16);
}

// ---------------------------------------------------------------------------
// K1: KNN (K=16, self-excluded) + GCN layer 1 (3->64) fused.
// 1024 blocks x 256 thr. Block = 64 nodes of one sample; 4 lanes per node,
// each lane scans a 512-candidate strip keeping a sorted top-16; strips are
// merged with shfl + bitonic min-merge. Full sample coords in LDS (32 KB).
// ---------------------------------------------------------------------------
__global__ __launch_bounds__(256, 4) void k1_knn_l1(
    const float* __restrict__ coords, const float* __restrict__ W1,
    const float* __restrict__ b1, int* __restrict__ nbr, u32* __restrict__ x1)
{
  __shared__ float4 c4[N_NODES];   // 32 KB
  __shared__ float  w1s[192];
  __shared__ float  b1s[64];
  const int tid   = threadIdx.x;
  const int s     = blockIdx.x >> 5;        // sample
  const int chunk = blockIdx.x & 31;        // 64-node chunk within sample
  const float* cs = coords + (size_t)s * (N_NODES * 3);
  for (int k = tid; k < N_NODES; k += 256)
    c4[k] = make_float4(cs[3*k], cs[3*k+1], cs[3*k+2], 0.0f);
  if (tid < 192) w1s[tid] = W1[tid];
  if (tid < 64)  b1s[tid] = b1[tid];
  __syncthreads();

  const int node = (chunk << 6) + (tid >> 2);   // sample-local node id
  const int sub  = tid & 3;                     // strip lane 0..3
  const float4 ci = c4[node];

  float ad[16]; int ai[16];
#pragma unroll
  for (int q = 0; q < 16; ++q) { ad[q] = INF; ai[q] = 0; }

  // scan this lane's strip: candidates it*16 + sub*4 + {0..3}
  for (int it = 0; it < 128; ++it) {
    const int base = (it << 4) + (sub << 2);
    float d[4];
#pragma unroll
    for (int q = 0; q < 4; ++q) {
      float4 cj = c4[base + q];
      float dx = ci.x - cj.x, dy = ci.y - cj.y, dz = ci.z - cj.z;
      float dd = fmaf(dz, dz, fmaf(dy, dy, dx * dx));
      d[q] = ((base + q) == node) ? INF : dd;
    }
    float mn = fminf(fminf(d[0], d[1]), fminf(d[2], d[3]));
    if (mn < ad[15]) {
#pragma unroll
      for (int q = 0; q < 4; ++q) {
        if (d[q] < ad[15]) {
          ad[15] = d[q]; ai[15] = base + q;
#pragma unroll
          for (int t = 14; t >= 0; --t) {
            float a = ad[t], b = ad[t+1];
            bool c = b < a;
            ad[t]   = c ? b : a;  ad[t+1] = c ? a : b;
            int ia = ai[t], ib = ai[t+1];
            ai[t]   = c ? ib : ia; ai[t+1] = c ? ia : ib;
          }
        }
      }
    }
  }

  // ---- merge 4 sorted strip-lists into top-16 of union (all via shfl) ----
  float bd[16]; int bi[16];
  // stage 1: pair (sub^1). Snapshot partner BEFORE modifying own regs.
#pragma unroll
  for (int q = 0; q < 16; ++q) {
    bd[q] = __shfl(ad[q], tid ^ 1);
    bi[q] = __shfl(ai[q], tid ^ 1);
  }
#pragma unroll
  for (int q = 0; q < 16; ++q) {   // half-cleaner: keep 16 smallest (bitonic)
    float nd = bd[15 - q]; int ni = bi[15 - q];
    bool t = nd < ad[q];
    ad[q] = t ? nd : ad[q];
    ai[q] = t ? ni : ai[q];
  }
  // bitonic cleanup -> ascending
#define CE(I, J) { bool t_ = ad[J] < ad[I]; float td_ = ad[I]; int ti_ = ai[I]; \
    ad[I] = t_ ? ad[J] : ad[I]; ai[I] = t_ ? ai[J] : ai[I];                     \
    ad[J] = t_ ? td_   : ad[J]; ai[J] = t_ ? ti_   : ai[J]; }
  CE(0,8) CE(1,9) CE(2,10) CE(3,11) CE(4,12) CE(5,13) CE(6,14) CE(7,15)
  CE(0,4) CE(1,5) CE(2,6)  CE(3,7)  CE(8,12) CE(9,13) CE(10,14) CE(11,15)
  CE(0,2) CE(1,3) CE(4,6)  CE(5,7)  CE(8,10) CE(9,11) CE(12,14) CE(13,15)
  CE(0,1) CE(2,3) CE(4,5)  CE(6,7)  CE(8,9)  CE(10,11) CE(12,13) CE(14,15)
#undef CE
  // stage 2: pair of pairs (sub^2). Final set may stay unsorted.
#pragma unroll
  for (int q = 0; q < 16; ++q) {
    bd[q] = __shfl(ad[q], tid ^ 2);
    bi[q] = __shfl(ai[q], tid ^ 2);
  }
#pragma unroll
  for (int q = 0; q < 16; ++q) {
    float nd = bd[15 - q]; int ni = bi[15 - q];
    bool t = nd < ad[q];
    ad[q] = t ? nd : ad[q];
    ai[q] = t ? ni : ai[q];
  }
  // every sublane now holds the node's final 16-NN multiset

  const size_t gnode = ((size_t)s << 11) + node;
  if (sub == 0) {
    int4* np_ = (int4*)(nbr + gnode * 16);
    np_[0] = make_int4(ai[0],  ai[1],  ai[2],  ai[3]);
    np_[1] = make_int4(ai[4],  ai[5],  ai[6],  ai[7]);
    np_[2] = make_int4(ai[8],  ai[9],  ai[10], ai[11]);
    np_[3] = make_int4(ai[12], ai[13], ai[14], ai[15]);
  }

  // layer 1: mean over {self + 16 nbrs}, 3x64 matmul + ReLU.
  float mx = ci.x, my = ci.y, mz = ci.z;
#pragma unroll
  for (int q = 0; q < 16; ++q) { float4 cn = c4[ai[q]]; mx += cn.x; my += cn.y; mz += cn.z; }
  const float inv = 1.0f / 17.0f;
  mx *= inv; my *= inv; mz *= inv;

  // this sublane computes outputs [sub*16, sub*16+16)
  u32 pk[8];
#pragma unroll
  for (int oo = 0; oo < 16; oo += 2) {
    const int o = (sub << 4) + oo;
    float v0 = fmaf(mz, w1s[128+o],   fmaf(my, w1s[64+o],   fmaf(mx, w1s[o],   b1s[o])));
    float v1 = fmaf(mz, w1s[128+o+1], fmaf(my, w1s[64+o+1], fmaf(mx, w1s[o+1], b1s[o+1])));
    pk[oo >> 1] = packbf(fmaxf(v0, 0.0f), fmaxf(v1, 0.0f));
  }
  uint4* xo = (uint4*)(x1 + gnode * 32 + (sub << 3));
  xo[0] = make_uint4(pk[0], pk[1], pk[2], pk[3]);
  xo[1] = make_uint4(pk[4], pk[5], pk[6], pk[7]);
}

// ---------------------------------------------------------------------------
// K2: gather-mean of x1 over {nbr, self} + GCN layer 2 (64->128) + ReLU.
// 1024 blocks: (node-chunk of 256) x (output slice of 32 channels).
// x2 stored slice-major: x2[slice][node][16 u32].
// ---------------------------------------------------------------------------
__global__ __launch_bounds__(256) void k2_gcn2(
    const u32* __restrict__ x1, const int* __restrict__ nbr,
    const float* __restrict__ W2, const float* __restrict__ b2,
    u32* __restrict__ x2)
{
  __shared__ float w2s[64 * 32];  // 8 KB slice
  __shared__ float b2s[32];
  const int tid   = threadIdx.x;
  const int chunk = blockIdx.x >> 2;
  const int sl    = blockIdx.x & 3;
  for (int k = tid; k < 64 * 32; k += 256)
    w2s[k] = W2[(k >> 5) * 128 + (sl << 5) + (k & 31)];
  if (tid < 32) b2s[tid] = b2[(sl << 5) + tid];
  __syncthreads();

  const size_t node = ((size_t)chunk << 8) + tid;
  const u32* x1base = x1 + ((node >> 11) << 11) * 32;
  const int  self   = (int)(node & 2047);
  const int* nb     = nbr + node * 16;

  float m1[64];
  {
    const uint4* r = (const uint4*)(x1base + (size_t)self * 32);
#pragma unroll
    for (int q = 0; q < 8; ++q) {
      uint4 v = r[q];
      m1[8*q+0] = bflo(v.x); m1[8*q+1] = bfhi(v.x);
      m1[8*q+2] = bflo(v.y); m1[8*q+3] = bfhi(v.y);
      m1[8*q+4] = bflo(v.z); m1[8*q+5] = bfhi(v.z);
      m1[8*q+6] = bflo(v.w); m1[8*q+7] = bfhi(v.w);
    }
  }
#pragma unroll
  for (int t = 0; t < 16; ++t) {
    const uint4* r = (const uint4*)(x1base + (size_t)nb[t] * 32);
#pragma unroll
    for (int q = 0; q < 8; ++q) {
      uint4 v = r[q];
      m1[8*q+0] += bflo(v.x); m1[8*q+1] += bfhi(v.x);
      m1[8*q+2] += bflo(v.y); m1[8*q+3] += bfhi(v.y);
      m1[8*q+4] += bflo(v.z); m1[8*q+5] += bfhi(v.z);
      m1[8*q+6] += bflo(v.w); m1[8*q+7] += bfhi(v.w);
    }
  }
  const float inv = 1.0f / 17.0f;
#pragma unroll
  for (int k = 0; k < 64; ++k) m1[k] *= inv;

  float acc[32];
#pragma unroll
  for (int q = 0; q < 32; ++q) acc[q] = b2s[q];
#pragma unroll
  for (int i = 0; i < 64; ++i) {
    const float4* w = (const float4*)&w2s[i * 32];
    float xi = m1[i];
#pragma unroll
    for (int q = 0; q < 8; ++q) {
      float4 wv = w[q];
      acc[4*q+0] = fmaf(xi, wv.x, acc[4*q+0]);
      acc[4*q+1] = fmaf(xi, wv.y, acc[4*q+1]);
      acc[4*q+2] = fmaf(xi, wv.z, acc[4*q+2]);
      acc[4*q+3] = fmaf(xi, wv.w, acc[4*q+3]);
    }
  }
  u32 p[16];
#pragma unroll
  for (int q = 0; q < 16; ++q)
    p[q] = packbf(fmaxf(acc[2*q], 0.0f), fmaxf(acc[2*q+1], 0.0f));
  uint4* o4 = (uint4*)(x2 + ((size_t)sl * 65536 + node) * 16);
  o4[0] = make_uint4(p[0],  p[1],  p[2],  p[3]);
  o4[1] = make_uint4(p[4],  p[5],  p[6],  p[7]);
  o4[2] = make_uint4(p[8],  p[9],  p[10], p[11]);
  o4[3] = make_uint4(p[12], p[13], p[14], p[15]);
}

// ---------------------------------------------------------------------------
// K3: final linear 128->128, f32 output.
// 1024 blocks: (node-chunk of 256) x (output slice of 32 channels).
// ---------------------------------------------------------------------------
__global__ __launch_bounds__(256) void k3_final(
    const u32* __restrict__ x2, const float* __restrict__ Wf,
    const float* __restrict__ bfv, float* __restrict__ out)
{
  __shared__ float wfs[128 * 32];  // 16 KB slice
  __shared__ float bfs[32];
  const int tid   = threadIdx.x;
  const int chunk = blockIdx.x >> 2;
  const int os    = blockIdx.x & 3;
  for (int k = tid; k < 128 * 32; k += 256)
    wfs[k] = Wf[(k >> 5) * 128 + (os << 5) + (k & 31)];
  if (tid < 32) bfs[tid] = bfv[tid + (os << 5)];
  __syncthreads();

  const size_t node = ((size_t)chunk << 8) + tid;

  float acc[32];
#pragma unroll
  for (int q = 0; q < 32; ++q) acc[q] = bfs[q];

#pragma unroll
  for (int sl = 0; sl < 4; ++sl) {   // input-channel slices of 32
    const uint4* xr = (const uint4*)(x2 + ((size_t)sl * 65536 + node) * 16);
    uint4 r0 = xr[0], r1 = xr[1], r2 = xr[2], r3 = xr[3];
    u32 rw[16] = { r0.x, r0.y, r0.z, r0.w, r1.x, r1.y, r1.z, r1.w,
                   r2.x, r2.y, r2.z, r2.w, r3.x, r3.y, r3.z, r3.w };
#pragma unroll
    for (int c = 0; c < 16; ++c) {
      const int ch = (sl << 5) + 2 * c;
      u32 v = rw[c];
      float x0 = bflo(v), x1v = bfhi(v);
      const float4* w0 = (const float4*)&wfs[ch * 32];
      const float4* w1 = (const float4*)&wfs[(ch + 1) * 32];
#pragma unroll
      for (int q = 0; q < 8; ++q) {
        float4 wv = w0[q];
        acc[4*q+0] = fmaf(x0, wv.x, acc[4*q+0]);
        acc[4*q+1] = fmaf(x0, wv.y, acc[4*q+1]);
        acc[4*q+2] = fmaf(x0, wv.z, acc[4*q+2]);
        acc[4*q+3] = fmaf(x0, wv.w, acc[4*q+3]);
      }
#pragma unroll
      for (int q = 0; q < 8; ++q) {
        float4 wv = w1[q];
        acc[4*q+0] = fmaf(x1v, wv.x, acc[4*q+0]);
        acc[4*q+1] = fmaf(x1v, wv.y, acc[4*q+1]);
        acc[4*q+2] = fmaf(x1v, wv.z, acc[4*q+2]);
        acc[4*q+3] = fmaf(x1v, wv.w, acc[4*q+3]);
      }
    }
  }

  float4* o4 = (float4*)(out + node * 128 + (os << 5));
#pragma unroll
  for (int q = 0; q < 8; ++q)
    o4[q] = make_float4(acc[4*q], acc[4*q+1], acc[4*q+2], acc[4*q+3]);
}

extern "C" void kernel_launch(void* const* d_in, const int* in_sizes, int n_in,
                              void* d_out, int out_size, void* d_ws, size_t ws_size,
                              hipStream_t stream) {
  const float* coords = (const float*)d_in[0];
  const float* W1 = (const float*)d_in[1];
  const float* b1 = (const float*)d_in[2];
  const float* W2 = (const float*)d_in[3];
  const float* b2 = (const float*)d_in[4];
  const float* Wf = (const float*)d_in[5];
  const float* bf = (const float*)d_in[6];
  float* out = (float*)d_out;

  char* ws = (char*)d_ws;
  int* nbr = (int*)ws;                                  //  4 MB: [32,2048,16] i32
  u32* x1  = (u32*)(ws + (size_t)4  * 1024 * 1024);     //  8 MB: [32,2048,64] bf16
  u32* x2  = (u32*)(ws + (size_t)12 * 1024 * 1024);     // 16 MB: [4][65536][16] u32 (bf16 pairs)

  k1_knn_l1<<<1024, 256, 0, stream>>>(coords, W1, b1, nbr, x1);
  k2_gcn2  <<<1024, 256, 0, stream>>>(x1, nbr, W2, b2, x2);
  k3_final <<<1024, 256, 0, stream>>>(x2, Wf, bf, out);
}

// Round 3
// 279.923 us; speedup vs baseline: 3.5223x; 2.3752x over previous
//
#include <hip/hip_runtime.h>
#include <hip/hip_bf16.h>

typedef unsigned int u32;

#define N_NODES 2048
#define INF __builtin_inff()

__device__ __forceinline__ float bflo(u32 u){ return __uint_as_float(u << 16); }
__device__ __forceinline__ float bfhi(u32 u){ return __uint_as_float(u & 0xFFFF0000u); }
__device__ __forceinline__ u32 packbf(float a, float b){
  u32 ua = __float_as_uint(a), ub = __float_as_uint(b);
  u32 ra = (ua + 0x7FFFu + ((ua >> 16) & 1u)) >> 16;
  u32 rb = (ub + 0x7FFFu + ((ub >> 16) & 1u)) >> 16;
  return ra | (rb << 16);
}

// branchless insert of v into sorted-ascending 16-list (distances only):
// one v_med3_f32 per slot, all 16 independent.
__device__ __forceinline__ void ins16(float (&ad)[16], float v) {
#pragma unroll
  for (int t = 15; t >= 1; --t)
    ad[t] = __builtin_amdgcn_fmed3f(v, ad[t-1], ad[t]);
  ad[0] = fminf(ad[0], v);
}

__device__ __forceinline__ float dist2(float cx, float cy, float cz,
                                       float jx, float jy, float jz) {
  float dx = cx - jx, dy = cy - jy, dz = cz - jz;
  return fmaf(dz, dz, fmaf(dy, dy, dx * dx));
}

// ---------------------------------------------------------------------------
// K1: exact KNN (K=16, self-excluded) + GCN layer 1 (3->64) fused.
// 1024 blocks x 256 thr; block = 64 nodes of one sample; 4 lanes/node.
// Scan 1: distances-only sorted top-16 per lane (med3 chain, branchless).
// Merge:  shfl + bitonic min-merge across 4 lanes -> tau = exact d16.
// Scan 2: recompute distances, compact indices d<=tau via LDS atomic append.
// ---------------------------------------------------------------------------
__global__ __launch_bounds__(256) void k1_knn_l1(
    const float* __restrict__ coords, const float* __restrict__ W1,
    const float* __restrict__ b1, int* __restrict__ nbr, u32* __restrict__ x1)
{
  __shared__ float xs[N_NODES], ys[N_NODES], zs[N_NODES];  // 24 KB SoA
  __shared__ float w1s[192];
  __shared__ float b1s[64];
  __shared__ u32   nbuf[64][16];   // 4 KB survivor indices
  __shared__ u32   ncnt[64];
  const int tid   = threadIdx.x;
  const int s     = blockIdx.x >> 5;
  const int chunk = blockIdx.x & 31;
  const float* cs = coords + (size_t)s * (N_NODES * 3);
  for (int k = tid; k < N_NODES; k += 256) {
    xs[k] = cs[3*k]; ys[k] = cs[3*k+1]; zs[k] = cs[3*k+2];
  }
  if (tid < 192) w1s[tid] = W1[tid];
  if (tid < 64)  { b1s[tid] = b1[tid]; ncnt[tid] = 0; }
  __syncthreads();

  const int node = (chunk << 6) + (tid >> 2);
  const int sub  = tid & 3;
  const int ln   = tid >> 2;
  const float cx = xs[node], cy = ys[node], cz = zs[node];

  float ad[16];
#pragma unroll
  for (int q = 0; q < 16; ++q) ad[q] = INF;

  const float4* xs4 = (const float4*)xs;
  const float4* ys4 = (const float4*)ys;
  const float4* zs4 = (const float4*)zs;

  // ---- scan 1: distances only, unconditional med3 insert ----
  for (int it = 0; it < 128; ++it) {
    const int v4 = (it << 2) + sub;
    float4 xv = xs4[v4], yv = ys4[v4], zv = zs4[v4];
    const int base = v4 << 2;
    float d0 = (base + 0 == node) ? INF : dist2(cx, cy, cz, xv.x, yv.x, zv.x);
    float d1 = (base + 1 == node) ? INF : dist2(cx, cy, cz, xv.y, yv.y, zv.y);
    float d2 = (base + 2 == node) ? INF : dist2(cx, cy, cz, xv.z, yv.z, zv.z);
    float d3 = (base + 3 == node) ? INF : dist2(cx, cy, cz, xv.w, yv.w, zv.w);
    ins16(ad, d0); ins16(ad, d1); ins16(ad, d2); ins16(ad, d3);
  }

  // ---- merge 4 sorted strip-lists (distances only) ----
  float bd[16];
#pragma unroll
  for (int q = 0; q < 16; ++q) bd[q] = __shfl(ad[q], tid ^ 1);
#pragma unroll
  for (int q = 0; q < 16; ++q) ad[q] = fminf(ad[q], bd[15 - q]);
  // bitonic cleanup -> ascending
#define CED(I, J) { float lo_ = fminf(ad[I], ad[J]); ad[J] = fmaxf(ad[I], ad[J]); ad[I] = lo_; }
  CED(0,8) CED(1,9) CED(2,10) CED(3,11) CED(4,12) CED(5,13) CED(6,14) CED(7,15)
  CED(0,4) CED(1,5) CED(2,6)  CED(3,7)  CED(8,12) CED(9,13) CED(10,14) CED(11,15)
  CED(0,2) CED(1,3) CED(4,6)  CED(5,7)  CED(8,10) CED(9,11) CED(12,14) CED(13,15)
  CED(0,1) CED(2,3) CED(4,5)  CED(6,7)  CED(8,9)  CED(10,11) CED(12,13) CED(14,15)
#undef CED
#pragma unroll
  for (int q = 0; q < 16; ++q) bd[q] = __shfl(ad[q], tid ^ 2);
#pragma unroll
  for (int q = 0; q < 16; ++q) ad[q] = fminf(ad[q], bd[15 - q]);
  // tau = max of final 16-multiset = exact 16th smallest distance
  float tau = ad[0];
#pragma unroll
  for (int q = 1; q < 16; ++q) tau = fmaxf(tau, ad[q]);

  // ---- scan 2: recompute (bitwise-identical) distances, compact indices ----
  for (int it = 0; it < 128; ++it) {
    const int v4 = (it << 2) + sub;
    float4 xv = xs4[v4], yv = ys4[v4], zv = zs4[v4];
    const int base = v4 << 2;
    float d0 = (base + 0 == node) ? INF : dist2(cx, cy, cz, xv.x, yv.x, zv.x);
    float d1 = (base + 1 == node) ? INF : dist2(cx, cy, cz, xv.y, yv.y, zv.y);
    float d2 = (base + 2 == node) ? INF : dist2(cx, cy, cz, xv.z, yv.z, zv.z);
    float d3 = (base + 3 == node) ? INF : dist2(cx, cy, cz, xv.w, yv.w, zv.w);
    if (d0 <= tau) { u32 p = atomicAdd(&ncnt[ln], 1u); if (p < 16u) nbuf[ln][p] = (u32)(base + 0); }
    if (d1 <= tau) { u32 p = atomicAdd(&ncnt[ln], 1u); if (p < 16u) nbuf[ln][p] = (u32)(base + 1); }
    if (d2 <= tau) { u32 p = atomicAdd(&ncnt[ln], 1u); if (p < 16u) nbuf[ln][p] = (u32)(base + 2); }
    if (d3 <= tau) { u32 p = atomicAdd(&ncnt[ln], 1u); if (p < 16u) nbuf[ln][p] = (u32)(base + 3); }
  }
  __syncthreads();   // make nbuf visible (cheap, once per block)

  const size_t gnode = ((size_t)s << 11) + node;
  uint4 nb = *(const uint4*)&nbuf[ln][sub << 2];
  *(int4*)(nbr + gnode * 16 + (sub << 2)) =
      make_int4((int)nb.x, (int)nb.y, (int)nb.z, (int)nb.w);

  // ---- layer 1: mean over {self + 16 nbrs}, 3x64 matmul + ReLU ----
  float sx, sy, sz;
  if (sub == 0) { sx = cx; sy = cy; sz = cz; } else { sx = 0.f; sy = 0.f; sz = 0.f; }
  sx += xs[nb.x] + xs[nb.y] + xs[nb.z] + xs[nb.w];
  sy += ys[nb.x] + ys[nb.y] + ys[nb.z] + ys[nb.w];
  sz += zs[nb.x] + zs[nb.y] + zs[nb.z] + zs[nb.w];
  sx += __shfl_xor(sx, 1); sx += __shfl_xor(sx, 2);
  sy += __shfl_xor(sy, 1); sy += __shfl_xor(sy, 2);
  sz += __shfl_xor(sz, 1); sz += __shfl_xor(sz, 2);
  const float inv = 1.0f / 17.0f;
  float mx = sx * inv, my = sy * inv, mz = sz * inv;

  // this sublane computes outputs [sub*16, sub*16+16)
  u32 pk[8];
#pragma unroll
  for (int oo = 0; oo < 16; oo += 2) {
    const int o = (sub << 4) + oo;
    float v0 = fmaf(mz, w1s[128+o],   fmaf(my, w1s[64+o],   fmaf(mx, w1s[o],   b1s[o])));
    float v1 = fmaf(mz, w1s[128+o+1], fmaf(my, w1s[64+o+1], fmaf(mx, w1s[o+1], b1s[o+1])));
    pk[oo >> 1] = packbf(fmaxf(v0, 0.0f), fmaxf(v1, 0.0f));
  }
  uint4* xo = (uint4*)(x1 + gnode * 32 + (sub << 3));
  xo[0] = make_uint4(pk[0], pk[1], pk[2], pk[3]);
  xo[1] = make_uint4(pk[4], pk[5], pk[6], pk[7]);
}

// ---------------------------------------------------------------------------
// K2: gather-mean of x1 over {nbr, self} + GCN layer 2 (64->128) + ReLU.
// 1024 blocks: (node-chunk of 256) x (output slice of 32 channels).
// x2 stored slice-major: x2[slice][node][16 u32].
// ---------------------------------------------------------------------------
__global__ __launch_bounds__(256) void k2_gcn2(
    const u32* __restrict__ x1, const int* __restrict__ nbr,
    const float* __restrict__ W2, const float* __restrict__ b2,
    u32* __restrict__ x2)
{
  __shared__ float w2s[64 * 32];  // 8 KB slice
  __shared__ float b2s[32];
  const int tid   = threadIdx.x;
  const int chunk = blockIdx.x >> 2;
  const int sl    = blockIdx.x & 3;
  for (int k = tid; k < 64 * 32; k += 256)
    w2s[k] = W2[(k >> 5) * 128 + (sl << 5) + (k & 31)];
  if (tid < 32) b2s[tid] = b2[(sl << 5) + tid];
  __syncthreads();

  const size_t node = ((size_t)chunk << 8) + tid;
  const u32* x1base = x1 + ((node >> 11) << 11) * 32;
  const int  self   = (int)(node & 2047);
  const int* nb     = nbr + node * 16;

  float m1[64];
  {
    const uint4* r = (const uint4*)(x1base + (size_t)self * 32);
#pragma unroll
    for (int q = 0; q < 8; ++q) {
      uint4 v = r[q];
      m1[8*q+0] = bflo(v.x); m1[8*q+1] = bfhi(v.x);
      m1[8*q+2] = bflo(v.y); m1[8*q+3] = bfhi(v.y);
      m1[8*q+4] = bflo(v.z); m1[8*q+5] = bfhi(v.z);
      m1[8*q+6] = bflo(v.w); m1[8*q+7] = bfhi(v.w);
    }
  }
#pragma unroll
  for (int t = 0; t < 16; ++t) {
    const uint4* r = (const uint4*)(x1base + (size_t)nb[t] * 32);
#pragma unroll
    for (int q = 0; q < 8; ++q) {
      uint4 v = r[q];
      m1[8*q+0] += bflo(v.x); m1[8*q+1] += bfhi(v.x);
      m1[8*q+2] += bflo(v.y); m1[8*q+3] += bfhi(v.y);
      m1[8*q+4] += bflo(v.z); m1[8*q+5] += bfhi(v.z);
      m1[8*q+6] += bflo(v.w); m1[8*q+7] += bfhi(v.w);
    }
  }
  const float inv = 1.0f / 17.0f;
#pragma unroll
  for (int k = 0; k < 64; ++k) m1[k] *= inv;

  float acc[32];
#pragma unroll
  for (int q = 0; q < 32; ++q) acc[q] = b2s[q];
#pragma unroll
  for (int i = 0; i < 64; ++i) {
    const float4* w = (const float4*)&w2s[i * 32];
    float xi = m1[i];
#pragma unroll
    for (int q = 0; q < 8; ++q) {
      float4 wv = w[q];
      acc[4*q+0] = fmaf(xi, wv.x, acc[4*q+0]);
      acc[4*q+1] = fmaf(xi, wv.y, acc[4*q+1]);
      acc[4*q+2] = fmaf(xi, wv.z, acc[4*q+2]);
      acc[4*q+3] = fmaf(xi, wv.w, acc[4*q+3]);
    }
  }
  u32 p[16];
#pragma unroll
  for (int q = 0; q < 16; ++q)
    p[q] = packbf(fmaxf(acc[2*q], 0.0f), fmaxf(acc[2*q+1], 0.0f));
  uint4* o4 = (uint4*)(x2 + ((size_t)sl * 65536 + node) * 16);
  o4[0] = make_uint4(p[0],  p[1],  p[2],  p[3]);
  o4[1] = make_uint4(p[4],  p[5],  p[6],  p[7]);
  o4[2] = make_uint4(p[8],  p[9],  p[10], p[11]);
  o4[3] = make_uint4(p[12], p[13], p[14], p[15]);
}

// ---------------------------------------------------------------------------
// K3: final linear 128->128, f32 output.
// 1024 blocks: (node-chunk of 256) x (output slice of 32 channels).
// ---------------------------------------------------------------------------
__global__ __launch_bounds__(256) void k3_final(
    const u32* __restrict__ x2, const float* __restrict__ Wf,
    const float* __restrict__ bfv, float* __restrict__ out)
{
  __shared__ float wfs[128 * 32];  // 16 KB slice
  __shared__ float bfs[32];
  const int tid   = threadIdx.x;
  const int chunk = blockIdx.x >> 2;
  const int os    = blockIdx.x & 3;
  for (int k = tid; k < 128 * 32; k += 256)
    wfs[k] = Wf[(k >> 5) * 128 + (os << 5) + (k & 31)];
  if (tid < 32) bfs[tid] = bfv[tid + (os << 5)];
  __syncthreads();

  const size_t node = ((size_t)chunk << 8) + tid;

  float acc[32];
#pragma unroll
  for (int q = 0; q < 32; ++q) acc[q] = bfs[q];

#pragma unroll
  for (int sl = 0; sl < 4; ++sl) {   // input-channel slices of 32
    const uint4* xr = (const uint4*)(x2 + ((size_t)sl * 65536 + node) * 16);
    uint4 r0 = xr[0], r1 = xr[1], r2 = xr[2], r3 = xr[3];
    u32 rw[16] = { r0.x, r0.y, r0.z, r0.w, r1.x, r1.y, r1.z, r1.w,
                   r2.x, r2.y, r2.z, r2.w, r3.x, r3.y, r3.z, r3.w };
#pragma unroll
    for (int c = 0; c < 16; ++c) {
      const int ch = (sl << 5) + 2 * c;
      u32 v = rw[c];
      float x0 = bflo(v), x1v = bfhi(v);
      const float4* w0 = (const float4*)&wfs[ch * 32];
      const float4* w1 = (const float4*)&wfs[(ch + 1) * 32];
#pragma unroll
      for (int q = 0; q < 8; ++q) {
        float4 wv = w0[q];
        acc[4*q+0] = fmaf(x0, wv.x, acc[4*q+0]);
        acc[4*q+1] = fmaf(x0, wv.y, acc[4*q+1]);
        acc[4*q+2] = fmaf(x0, wv.z, acc[4*q+2]);
        acc[4*q+3] = fmaf(x0, wv.w, acc[4*q+3]);
      }
#pragma unroll
      for (int q = 0; q < 8; ++q) {
        float4 wv = w1[q];
        acc[4*q+0] = fmaf(x1v, wv.x, acc[4*q+0]);
        acc[4*q+1] = fmaf(x1v, wv.y, acc[4*q+1]);
        acc[4*q+2] = fmaf(x1v, wv.z, acc[4*q+2]);
        acc[4*q+3] = fmaf(x1v, wv.w, acc[4*q+3]);
      }
    }
  }

  float4* o4 = (float4*)(out + node * 128 + (os << 5));
#pragma unroll
  for (int q = 0; q < 8; ++q)
    o4[q] = make_float4(acc[4*q], acc[4*q+1], acc[4*q+2], acc[4*q+3]);
}

extern "C" void kernel_launch(void* const* d_in, const int* in_sizes, int n_in,
                              void* d_out, int out_size, void* d_ws, size_t ws_size,
                              hipStream_t stream) {
  const float* coords = (const float*)d_in[0];
  const float* W1 = (const float*)d_in[1];
  const float* b1 = (const float*)d_in[2];
  const float* W2 = (const float*)d_in[3];
  const float* b2 = (const float*)d_in[4];
  const float* Wf = (const float*)d_in[5];
  const float* bf = (const float*)d_in[6];
  float* out = (float*)d_out;

  char* ws = (char*)d_ws;
  int* nbr = (int*)ws;                                  //  4 MB: [32,2048,16] i32
  u32* x1  = (u32*)(ws + (size_t)4  * 1024 * 1024);     //  8 MB: [32,2048,64] bf16
  u32* x2  = (u32*)(ws + (size_t)12 * 1024 * 1024);     // 16 MB: [4][65536][16] u32 (bf16 pairs)

  k1_knn_l1<<<1024, 256, 0, stream>>>(coords, W1, b1, nbr, x1);
  k2_gcn2  <<<1024, 256, 0, stream>>>(x1, nbr, W2, b2, x2);
  k3_final <<<1024, 256, 0, stream>>>(x2, Wf, bf, out);
}

// Round 4
// 189.568 us; speedup vs baseline: 5.2012x; 1.4766x over previous
//
#include <hip/hip_runtime.h>
#include <hip/hip_bf16.h>

typedef unsigned int u32;
typedef __attribute__((ext_vector_type(8))) short bf16x8;
typedef __attribute__((ext_vector_type(4))) float f32x4;

#define N_NODES 2048
#define INF __builtin_inff()

__device__ __forceinline__ float bflo(u32 u){ return __uint_as_float(u << 16); }
__device__ __forceinline__ float bfhi(u32 u){ return __uint_as_float(u & 0xFFFF0000u); }
__device__ __forceinline__ u32 packbf(float a, float b){
  u32 ua = __float_as_uint(a), ub = __float_as_uint(b);
  u32 ra = (ua + 0x7FFFu + ((ua >> 16) & 1u)) >> 16;
  u32 rb = (ub + 0x7FFFu + ((ub >> 16) & 1u)) >> 16;
  return ra | (rb << 16);
}

// branchless insert of v into sorted-ascending 16-list (distances only)
__device__ __forceinline__ void ins16(float (&ad)[16], float v) {
#pragma unroll
  for (int t = 15; t >= 1; --t)
    ad[t] = __builtin_amdgcn_fmed3f(v, ad[t-1], ad[t]);
  ad[0] = fminf(ad[0], v);
}

__device__ __forceinline__ float dist2(float cx, float cy, float cz,
                                       float jx, float jy, float jz) {
  float dx = cx - jx, dy = cy - jy, dz = cz - jz;
  return fmaf(dz, dz, fmaf(dy, dy, dx * dx));
}

// ---------------------------------------------------------------------------
// K1: exact KNN (K=16, self-excluded) + GCN layer 1 (3->64) fused.
// (unchanged from round 3)
// ---------------------------------------------------------------------------
__global__ __launch_bounds__(256) void k1_knn_l1(
    const float* __restrict__ coords, const float* __restrict__ W1,
    const float* __restrict__ b1, int* __restrict__ nbr, u32* __restrict__ x1)
{
  __shared__ float xs[N_NODES], ys[N_NODES], zs[N_NODES];
  __shared__ float w1s[192];
  __shared__ float b1s[64];
  __shared__ u32   nbuf[64][16];
  __shared__ u32   ncnt[64];
  const int tid   = threadIdx.x;
  const int s     = blockIdx.x >> 5;
  const int chunk = blockIdx.x & 31;
  const float* cs = coords + (size_t)s * (N_NODES * 3);
  for (int k = tid; k < N_NODES; k += 256) {
    xs[k] = cs[3*k]; ys[k] = cs[3*k+1]; zs[k] = cs[3*k+2];
  }
  if (tid < 192) w1s[tid] = W1[tid];
  if (tid < 64)  { b1s[tid] = b1[tid]; ncnt[tid] = 0; }
  __syncthreads();

  const int node = (chunk << 6) + (tid >> 2);
  const int sub  = tid & 3;
  const int ln   = tid >> 2;
  const float cx = xs[node], cy = ys[node], cz = zs[node];

  float ad[16];
#pragma unroll
  for (int q = 0; q < 16; ++q) ad[q] = INF;

  const float4* xs4 = (const float4*)xs;
  const float4* ys4 = (const float4*)ys;
  const float4* zs4 = (const float4*)zs;

  for (int it = 0; it < 128; ++it) {
    const int v4 = (it << 2) + sub;
    float4 xv = xs4[v4], yv = ys4[v4], zv = zs4[v4];
    const int base = v4 << 2;
    float d0 = (base + 0 == node) ? INF : dist2(cx, cy, cz, xv.x, yv.x, zv.x);
    float d1 = (base + 1 == node) ? INF : dist2(cx, cy, cz, xv.y, yv.y, zv.y);
    float d2 = (base + 2 == node) ? INF : dist2(cx, cy, cz, xv.z, yv.z, zv.z);
    float d3 = (base + 3 == node) ? INF : dist2(cx, cy, cz, xv.w, yv.w, zv.w);
    ins16(ad, d0); ins16(ad, d1); ins16(ad, d2); ins16(ad, d3);
  }

  float bd[16];
#pragma unroll
  for (int q = 0; q < 16; ++q) bd[q] = __shfl(ad[q], tid ^ 1);
#pragma unroll
  for (int q = 0; q < 16; ++q) ad[q] = fminf(ad[q], bd[15 - q]);
#define CED(I, J) { float lo_ = fminf(ad[I], ad[J]); ad[J] = fmaxf(ad[I], ad[J]); ad[I] = lo_; }
  CED(0,8) CED(1,9) CED(2,10) CED(3,11) CED(4,12) CED(5,13) CED(6,14) CED(7,15)
  CED(0,4) CED(1,5) CED(2,6)  CED(3,7)  CED(8,12) CED(9,13) CED(10,14) CED(11,15)
  CED(0,2) CED(1,3) CED(4,6)  CED(5,7)  CED(8,10) CED(9,11) CED(12,14) CED(13,15)
  CED(0,1) CED(2,3) CED(4,5)  CED(6,7)  CED(8,9)  CED(10,11) CED(12,13) CED(14,15)
#undef CED
#pragma unroll
  for (int q = 0; q < 16; ++q) bd[q] = __shfl(ad[q], tid ^ 2);
#pragma unroll
  for (int q = 0; q < 16; ++q) ad[q] = fminf(ad[q], bd[15 - q]);
  float tau = ad[0];
#pragma unroll
  for (int q = 1; q < 16; ++q) tau = fmaxf(tau, ad[q]);

  for (int it = 0; it < 128; ++it) {
    const int v4 = (it << 2) + sub;
    float4 xv = xs4[v4], yv = ys4[v4], zv = zs4[v4];
    const int base = v4 << 2;
    float d0 = (base + 0 == node) ? INF : dist2(cx, cy, cz, xv.x, yv.x, zv.x);
    float d1 = (base + 1 == node) ? INF : dist2(cx, cy, cz, xv.y, yv.y, zv.y);
    float d2 = (base + 2 == node) ? INF : dist2(cx, cy, cz, xv.z, yv.z, zv.z);
    float d3 = (base + 3 == node) ? INF : dist2(cx, cy, cz, xv.w, yv.w, zv.w);
    if (d0 <= tau) { u32 p = atomicAdd(&ncnt[ln], 1u); if (p < 16u) nbuf[ln][p] = (u32)(base + 0); }
    if (d1 <= tau) { u32 p = atomicAdd(&ncnt[ln], 1u); if (p < 16u) nbuf[ln][p] = (u32)(base + 1); }
    if (d2 <= tau) { u32 p = atomicAdd(&ncnt[ln], 1u); if (p < 16u) nbuf[ln][p] = (u32)(base + 2); }
    if (d3 <= tau) { u32 p = atomicAdd(&ncnt[ln], 1u); if (p < 16u) nbuf[ln][p] = (u32)(base + 3); }
  }
  __syncthreads();

  const size_t gnode = ((size_t)s << 11) + node;
  uint4 nb = *(const uint4*)&nbuf[ln][sub << 2];
  *(int4*)(nbr + gnode * 16 + (sub << 2)) =
      make_int4((int)nb.x, (int)nb.y, (int)nb.z, (int)nb.w);

  float sx, sy, sz;
  if (sub == 0) { sx = cx; sy = cy; sz = cz; } else { sx = 0.f; sy = 0.f; sz = 0.f; }
  sx += xs[nb.x] + xs[nb.y] + xs[nb.z] + xs[nb.w];
  sy += ys[nb.x] + ys[nb.y] + ys[nb.z] + ys[nb.w];
  sz += zs[nb.x] + zs[nb.y] + zs[nb.z] + zs[nb.w];
  sx += __shfl_xor(sx, 1); sx += __shfl_xor(sx, 2);
  sy += __shfl_xor(sy, 1); sy += __shfl_xor(sy, 2);
  sz += __shfl_xor(sz, 1); sz += __shfl_xor(sz, 2);
  const float inv = 1.0f / 17.0f;
  float mx = sx * inv, my = sy * inv, mz = sz * inv;

  u32 pk[8];
#pragma unroll
  for (int oo = 0; oo < 16; oo += 2) {
    const int o = (sub << 4) + oo;
    float v0 = fmaf(mz, w1s[128+o],   fmaf(my, w1s[64+o],   fmaf(mx, w1s[o],   b1s[o])));
    float v1 = fmaf(mz, w1s[128+o+1], fmaf(my, w1s[64+o+1], fmaf(mx, w1s[o+1], b1s[o+1])));
    pk[oo >> 1] = packbf(fmaxf(v0, 0.0f), fmaxf(v1, 0.0f));
  }
  uint4* xo = (uint4*)(x1 + gnode * 32 + (sub << 3));
  xo[0] = make_uint4(pk[0], pk[1], pk[2], pk[3]);
  xo[1] = make_uint4(pk[4], pk[5], pk[6], pk[7]);
}

// ---------------------------------------------------------------------------
// K2: gather-mean of x1 over {nbr,self} -> bf16 A-tile (LDS, swizzled) ->
// MFMA GEMM [128 nodes x 64] @ [64 x 128] with hi/lo-split bf16 weights ->
// ReLU -> x2 bf16. 512 blocks x 256 thr (4 waves; wave = 32 node-rows).
// ---------------------------------------------------------------------------
__global__ __launch_bounds__(256) void k2_gcn2(
    const u32* __restrict__ x1, const int* __restrict__ nbr,
    const float* __restrict__ W2, const float* __restrict__ b2,
    u32* __restrict__ x2)
{
  __shared__ uint4 AldsV[1024];   // 16 KB: [128 rows][128 B] (64 ch bf16, swz)
  __shared__ uint4 BhiV[1024];    // 16 KB: [128 n][64 k] bf16 hi, swz
  __shared__ uint4 BloV[1024];    // 16 KB: lo
  char* Alds = (char*)AldsV; char* Bhi = (char*)BhiV; char* Blo = (char*)BloV;
  const int tid   = threadIdx.x;
  const int node0 = blockIdx.x << 7;

  // stage W2 -> transposed [n][k] bf16 hi/lo
#pragma unroll
  for (int i = 0; i < 32; ++i) {
    int e = tid + (i << 8);             // 0..8191
    int k = e >> 7, n = e & 127;
    float w = W2[e];
    u32 hb = packbf(w, 0.0f) & 0xFFFFu;
    float whi = __uint_as_float(hb << 16);
    u32 lb = packbf(w - whi, 0.0f) & 0xFFFFu;
    int byte = n * 128 + ((2 * k) ^ ((n & 7) << 4));
    *(unsigned short*)(Bhi + byte) = (unsigned short)hb;
    *(unsigned short*)(Blo + byte) = (unsigned short)lb;
  }

  // aggregate mean (2 threads/node, 32 ch each) -> A-tile
  {
    const int r = tid >> 1, half = tid & 1;
    const size_t gnode = (size_t)node0 + r;
    const u32* selfp = x1 + gnode * 32 + half * 16;
    const u32* x1s   = x1 + ((gnode >> 11) << 11) * 32;
    const int* nb    = nbr + gnode * 16;
    float a[32];
#pragma unroll
    for (int q = 0; q < 4; ++q) {
      uint4 v = *(const uint4*)(selfp + (q << 2));
      a[8*q+0] = bflo(v.x); a[8*q+1] = bfhi(v.x);
      a[8*q+2] = bflo(v.y); a[8*q+3] = bfhi(v.y);
      a[8*q+4] = bflo(v.z); a[8*q+5] = bfhi(v.z);
      a[8*q+6] = bflo(v.w); a[8*q+7] = bfhi(v.w);
    }
#pragma unroll
    for (int t = 0; t < 16; ++t) {
      const u32* rp = x1s + (size_t)nb[t] * 32 + half * 16;
#pragma unroll
      for (int q = 0; q < 4; ++q) {
        uint4 v = *(const uint4*)(rp + (q << 2));
        a[8*q+0] += bflo(v.x); a[8*q+1] += bfhi(v.x);
        a[8*q+2] += bflo(v.y); a[8*q+3] += bfhi(v.y);
        a[8*q+4] += bflo(v.z); a[8*q+5] += bfhi(v.z);
        a[8*q+6] += bflo(v.w); a[8*q+7] += bfhi(v.w);
      }
    }
    const float inv = 1.0f / 17.0f;
    u32 pk[16];
#pragma unroll
    for (int j = 0; j < 16; ++j)
      pk[j] = packbf(a[2*j] * inv, a[2*j+1] * inv);
#pragma unroll
    for (int q = 0; q < 4; ++q) {
      int byte = r * 128 + ((((half << 6) + (q << 4))) ^ ((r & 7) << 4));
      *(uint4*)(Alds + byte) = make_uint4(pk[4*q], pk[4*q+1], pk[4*q+2], pk[4*q+3]);
    }
  }
  __syncthreads();

  const int lane = tid & 63, wv = tid >> 6;
  const int cl = lane & 15, kg = lane >> 4;

  f32x4 acc[2][8];
#pragma unroll
  for (int rt = 0; rt < 2; ++rt)
#pragma unroll
    for (int ct = 0; ct < 8; ++ct) {
      float bv = b2[(ct << 4) + cl];
      acc[rt][ct] = (f32x4){bv, bv, bv, bv};
    }

#pragma unroll
  for (int ks = 0; ks < 2; ++ks) {
    const int kb = (ks << 6) + (kg << 4);
    bf16x8 af[2];
#pragma unroll
    for (int rt = 0; rt < 2; ++rt) {
      int row = (wv << 5) + (rt << 4) + cl;
      af[rt] = *(const bf16x8*)(Alds + row * 128 + (kb ^ ((row & 7) << 4)));
    }
#pragma unroll
    for (int ct = 0; ct < 8; ++ct) {
      int n = (ct << 4) + cl;
      int byte = n * 128 + (kb ^ ((n & 7) << 4));
      bf16x8 bh = *(const bf16x8*)(Bhi + byte);
      bf16x8 bl = *(const bf16x8*)(Blo + byte);
#pragma unroll
      for (int rt = 0; rt < 2; ++rt) {
        acc[rt][ct] = __builtin_amdgcn_mfma_f32_16x16x32_bf16(af[rt], bh, acc[rt][ct], 0, 0, 0);
        acc[rt][ct] = __builtin_amdgcn_mfma_f32_16x16x32_bf16(af[rt], bl, acc[rt][ct], 0, 0, 0);
      }
    }
  }

  // ReLU + bf16 store: C/D layout col=lane&15, row=4*(lane>>4)+reg
  unsigned short* x2h = (unsigned short*)x2;
#pragma unroll
  for (int rt = 0; rt < 2; ++rt)
#pragma unroll
    for (int ct = 0; ct < 8; ++ct) {
      int colg = (ct << 4) + cl;
      int nr0  = node0 + (wv << 5) + (rt << 4) + (kg << 2);
#pragma unroll
      for (int r = 0; r < 4; ++r) {
        float v = fmaxf(acc[rt][ct][r], 0.0f);
        x2h[(size_t)(nr0 + r) * 128 + colg] = (unsigned short)(packbf(v, 0.0f) & 0xFFFFu);
      }
    }
}

// ---------------------------------------------------------------------------
// K3: final linear 128->128 via MFMA, hi/lo-split weights, f32 out.
// 1024 blocks: (128-node tile) x (64-col half). 256 thr = 4 waves.
// ---------------------------------------------------------------------------
__global__ __launch_bounds__(256) void k3_final(
    const u32* __restrict__ x2, const float* __restrict__ Wf,
    const float* __restrict__ bfv, float* __restrict__ out)
{
  __shared__ uint4 AldsV[2048];   // 32 KB: [128 rows][256 B] (128 ch bf16, swz)
  __shared__ uint4 BhiV[1024];    // 16 KB: [64 n][128 k] bf16 hi, swz
  __shared__ uint4 BloV[1024];
  char* Alds = (char*)AldsV; char* Bhi = (char*)BhiV; char* Blo = (char*)BloV;
  const int tid   = threadIdx.x;
  const int node0 = (blockIdx.x >> 1) << 7;
  const int ch0   = (blockIdx.x & 1) << 6;

  // stage Wf col-half -> transposed [n][k] bf16 hi/lo
#pragma unroll
  for (int i = 0; i < 32; ++i) {
    int e = tid + (i << 8);             // 0..8191
    int k = e >> 6, n = e & 63;
    float w = Wf[k * 128 + ch0 + n];
    u32 hb = packbf(w, 0.0f) & 0xFFFFu;
    float whi = __uint_as_float(hb << 16);
    u32 lb = packbf(w - whi, 0.0f) & 0xFFFFu;
    int byte = n * 256 + ((2 * k) ^ ((n & 15) << 4));
    *(unsigned short*)(Bhi + byte) = (unsigned short)hb;
    *(unsigned short*)(Blo + byte) = (unsigned short)lb;
  }

  // stage x2 tile -> A (swizzled)
  {
    const int r = tid >> 1, half = tid & 1;
    const u32* src = x2 + (size_t)(node0 + r) * 64 + half * 32;
#pragma unroll
    for (int q = 0; q < 8; ++q) {
      uint4 v = *(const uint4*)(src + (q << 2));
      int byte = r * 256 + ((((half << 7) + (q << 4))) ^ ((r & 15) << 4));
      *(uint4*)(Alds + byte) = v;
    }
  }
  __syncthreads();

  const int lane = tid & 63, wv = tid >> 6;
  const int cl = lane & 15, kg = lane >> 4;

  f32x4 acc[2][4];
#pragma unroll
  for (int rt = 0; rt < 2; ++rt)
#pragma unroll
    for (int ct = 0; ct < 4; ++ct) {
      float bv = bfv[ch0 + (ct << 4) + cl];
      acc[rt][ct] = (f32x4){bv, bv, bv, bv};
    }

#pragma unroll
  for (int ks = 0; ks < 4; ++ks) {
    const int kb = (ks << 6) + (kg << 4);
    bf16x8 af[2];
#pragma unroll
    for (int rt = 0; rt < 2; ++rt) {
      int row = (wv << 5) + (rt << 4) + cl;
      af[rt] = *(const bf16x8*)(Alds + row * 256 + (kb ^ ((row & 15) << 4)));
    }
#pragma unroll
    for (int ct = 0; ct < 4; ++ct) {
      int n = (ct << 4) + cl;
      int byte = n * 256 + (kb ^ ((n & 15) << 4));
      bf16x8 bh = *(const bf16x8*)(Bhi + byte);
      bf16x8 bl = *(const bf16x8*)(Blo + byte);
#pragma unroll
      for (int rt = 0; rt < 2; ++rt) {
        acc[rt][ct] = __builtin_amdgcn_mfma_f32_16x16x32_bf16(af[rt], bh, acc[rt][ct], 0, 0, 0);
        acc[rt][ct] = __builtin_amdgcn_mfma_f32_16x16x32_bf16(af[rt], bl, acc[rt][ct], 0, 0, 0);
      }
    }
  }

#pragma unroll
  for (int rt = 0; rt < 2; ++rt)
#pragma unroll
    for (int ct = 0; ct < 4; ++ct) {
      int col = ch0 + (ct << 4) + cl;
      int nr0 = node0 + (wv << 5) + (rt << 4) + (kg << 2);
#pragma unroll
      for (int r = 0; r < 4; ++r)
        out[(size_t)(nr0 + r) * 128 + col] = acc[rt][ct][r];
    }
}

extern "C" void kernel_launch(void* const* d_in, const int* in_sizes, int n_in,
                              void* d_out, int out_size, void* d_ws, size_t ws_size,
                              hipStream_t stream) {
  const float* coords = (const float*)d_in[0];
  const float* W1 = (const float*)d_in[1];
  const float* b1 = (const float*)d_in[2];
  const float* W2 = (const float*)d_in[3];
  const float* b2 = (const float*)d_in[4];
  const float* Wf = (const float*)d_in[5];
  const float* bf = (const float*)d_in[6];
  float* out = (float*)d_out;

  char* ws = (char*)d_ws;
  int* nbr = (int*)ws;                                  //  4 MB: [32,2048,16] i32
  u32* x1  = (u32*)(ws + (size_t)4  * 1024 * 1024);     //  8 MB: [32,2048,64] bf16
  u32* x2  = (u32*)(ws + (size_t)12 * 1024 * 1024);     // 16 MB: [65536,128] bf16

  k1_knn_l1<<<1024, 256, 0, stream>>>(coords, W1, b1, nbr, x1);
  k2_gcn2  <<< 512, 256, 0, stream>>>(x1, nbr, W2, b2, x2);
  k3_final <<<1024, 256, 0, stream>>>(x2, Wf, bf, out);
}